// Round 4
// baseline (462.814 us; speedup 1.0000x reference)
//
#include <hip/hip_runtime.h>
#include <hip/hip_bf16.h>

#define N_FEAT 8192
#define D_MODEL 256
#define HEADS 4
#define CELLS 32
#define BATCH 4096
#define HC 128          // HEADS*CELLS
#define NT 16           // n-rows per reps block
#define DC 64           // d-chunk
#define KSPLIT 16
#define KCH (N_FEAT / KSPLIT)   // 512
#define BK 64
#define LDSW 72         // LDS row stride in shorts (144 B, 16B-aligned, breaks 16-way)

typedef __attribute__((ext_vector_type(8))) short bf16x8;
typedef __attribute__((ext_vector_type(4))) float f32x4;

__device__ __forceinline__ unsigned short f32_to_bf16(float f) {
    union { float f; unsigned u; } v; v.f = f;
    unsigned r = v.u + 0x7fffu + ((v.u >> 16) & 1u);
    return (unsigned short)(r >> 16);
}

__device__ __forceinline__ unsigned pack_bf16x2(float lo, float hi) {
    return (unsigned)f32_to_bf16(lo) | ((unsigned)f32_to_bf16(hi) << 16);
}

// ---------------------------------------------------------------------------
// Stage 1 (fused): tropical scores -> top-2 -> sigmoid blend -> reps + repsT
// NT=16 rows/block, grid 512 (2 blocks/CU). Lane maps chosen for LDS banks:
//   hc = tx + 32j  (wS reads 4-way, was 16-way)
//   n  = ty + 8i   (latS reads conflict-free broadcast)
// ---------------------------------------------------------------------------
__global__ __launch_bounds__(256) void reps_kernel(
    const float* __restrict__ proj, const float* __restrict__ rw,
    const float* __restrict__ rb, const float* __restrict__ cb,
    unsigned short* __restrict__ reps_bf, unsigned short* __restrict__ repsT)
{
    __shared__ float latS[NT][DC + 4];     // stride 68 floats
    __shared__ float wS[HC][DC + 4];
    __shared__ float sc[NT][HC + 4];
    __shared__ float gateS[NT][HEADS];
    __shared__ int   widxS[NT][HEADS], ridxS[NT][HEADS];

    const int t = threadIdx.x;
    const int nbase = blockIdx.x * NT;
    const int tx = t & 31, ty = t >> 5;

    float acc[2][4];
    #pragma unroll
    for (int i = 0; i < 2; ++i)
        #pragma unroll
        for (int j = 0; j < 4; ++j)
            acc[i][j] = -3.4e38f;

    for (int dk = 0; dk < D_MODEL; dk += DC) {
        __syncthreads();
        // latS: 16x64 = 256 float4, 1 per thread
        {
            const int row = t >> 4, c4 = t & 15;
            float4 v = *(const float4*)&proj[(long)(nbase + row) * D_MODEL + dk + c4 * 4];
            *(float4*)&latS[row][c4 * 4] = v;
        }
        // wS: 128x64 = 2048 float4, 8 per thread
        {
            int f = t;
            #pragma unroll
            for (int i = 0; i < 8; ++i, f += 256) {
                const int row = f >> 4, c4 = f & 15;
                float4 v = *(const float4*)&rw[(long)row * D_MODEL + dk + c4 * 4];
                *(float4*)&wS[row][c4 * 4] = v;
            }
        }
        __syncthreads();

        #pragma unroll 4
        for (int d = 0; d < DC; d += 4) {
            float4 la[2], wv[4];
            #pragma unroll
            for (int i = 0; i < 2; ++i) la[i] = *(const float4*)&latS[ty + 8 * i][d];
            #pragma unroll
            for (int j = 0; j < 4; ++j) wv[j] = *(const float4*)&wS[tx + 32 * j][d];
            #pragma unroll
            for (int i = 0; i < 2; ++i)
                #pragma unroll
                for (int j = 0; j < 4; ++j) {
                    float m01 = fmaxf(la[i].x + wv[j].x, la[i].y + wv[j].y);
                    float m23 = fmaxf(la[i].z + wv[j].z, la[i].w + wv[j].w);
                    acc[i][j] = fmaxf(acc[i][j], fmaxf(m01, m23));
                }
        }
    }

    // sc[n][hc], hc = tx + 32j (hc == h*32 + c directly)
    #pragma unroll
    for (int j = 0; j < 4; ++j) {
        const float rbv = rb[tx + 32 * j];
        #pragma unroll
        for (int i = 0; i < 2; ++i)
            sc[ty + 8 * i][tx + 32 * j] = acc[i][j] + rbv;
    }
    __syncthreads();

    if (t < NT * HEADS) {
        const int n = t >> 2, h = t & 3;
        float v1 = -3.4e38f, v2 = -3.4e38f; int i1 = 0, i2 = 0;
        #pragma unroll
        for (int c = 0; c < CELLS; ++c) {
            float s = sc[n][h * CELLS + c];
            if (s > v1) { v2 = v1; i2 = i1; v1 = s; i1 = c; }
            else if (s > v2) { v2 = s; i2 = c; }
        }
        gateS[n][h] = 1.0f / (1.0f + __expf(-(v1 - v2)));
        widxS[n][h] = i1; ridxS[n][h] = i2;
    }
    __syncthreads();

    // blend: thread t owns column d=t for all NT rows; vals in registers
    float vals[NT];
    #pragma unroll
    for (int r = 0; r < NT; ++r)
        vals[r] = proj[(long)(nbase + r) * D_MODEL + t];
    #pragma unroll
    for (int h = 0; h < HEADS; ++h) {
        #pragma unroll
        for (int r = 0; r < NT; ++r) {
            const float g = gateS[r][h];
            const float wv = cb[(long)(h * CELLS + widxS[r][h]) * D_MODEL + t];
            const float rv = cb[(long)(h * CELLS + ridxS[r][h]) * D_MODEL + t];
            vals[r] += g * wv + (1.0f - g) * rv;   // CODE_SCALE = 1
        }
    }
    // reps row-major (coalesced 512B rows)
    #pragma unroll
    for (int r = 0; r < NT; ++r)
        reps_bf[(long)(nbase + r) * D_MODEL + t] = f32_to_bf16(vals[r]);
    // repsT: thread-contiguous 32 B at repsT[t][nbase..nbase+15]
    unsigned pk[NT / 2];
    #pragma unroll
    for (int i = 0; i < NT / 2; ++i)
        pk[i] = pack_bf16x2(vals[2 * i], vals[2 * i + 1]);
    uint4* dst = (uint4*)(repsT + (long)t * N_FEAT + nbase);
    dst[0] = *(const uint4*)&pk[0];
    dst[1] = *(const uint4*)&pk[4];
}

// ---------------------------------------------------------------------------
// Stage 2: hidden_part[ks] = x[:, ks-chunk] @ reps[ks-chunk, :]  (f32 out)
// 128x128 tile, BK=64 (8 iters), reg-prefetch distance 1; f32 partials
// ---------------------------------------------------------------------------
__global__ __launch_bounds__(256, 3) void gemm1_kernel(
    const float* __restrict__ x, const unsigned short* __restrict__ repsT,
    float* __restrict__ hidden_part)
{
    __shared__ unsigned short As[128 * LDSW];
    __shared__ unsigned short Bs[128 * LDSW];

    const int m0 = blockIdx.y * 128;
    const int n0 = blockIdx.x * 128;
    const int ks = blockIdx.z;
    const int t = threadIdx.x;
    const int wave = t >> 6, lane = t & 63;
    const int wm = (wave >> 1) * 64, wn = (wave & 1) * 64;
    const int quad = lane >> 4, l16 = lane & 15;

    f32x4 acc[4][4];
    #pragma unroll
    for (int i = 0; i < 4; ++i)
        #pragma unroll
        for (int j = 0; j < 4; ++j)
            acc[i][j] = (f32x4){0.f, 0.f, 0.f, 0.f};

    const int row = t >> 1, half = t & 1;
    const float* xsrc = x + (long)(m0 + row) * N_FEAT + ks * KCH + half * 32;
    const unsigned short* bsrc = repsT + (long)(n0 + row) * N_FEAT + ks * KCH + half * 32;
    unsigned short* aw = &As[row * LDSW + half * 32];
    unsigned short* bw = &Bs[row * LDSW + half * 32];

    // prefetch iter 0: 128 B of x (8 float4), 64 B of B (4 uint4)
    float4 fa[8]; uint4 fb[4];
    #pragma unroll
    for (int i = 0; i < 8; ++i) fa[i] = ((const float4*)xsrc)[i];
    #pragma unroll
    for (int i = 0; i < 4; ++i) fb[i] = ((const uint4*)bsrc)[i];

    for (int it = 0; it < KCH / BK; ++it) {
        // convert A f32->bf16 (vmcnt wait lands here)
        unsigned pk[16];
        #pragma unroll
        for (int i = 0; i < 8; ++i) {
            pk[2 * i]     = pack_bf16x2(fa[i].x, fa[i].y);
            pk[2 * i + 1] = pack_bf16x2(fa[i].z, fa[i].w);
        }
        __syncthreads();
        #pragma unroll
        for (int i = 0; i < 4; ++i)
            *(uint4*)(aw + i * 8) = *(const uint4*)&pk[4 * i];
        #pragma unroll
        for (int i = 0; i < 4; ++i)
            *(uint4*)(bw + i * 8) = fb[i];
        __syncthreads();

        // issue next iter's loads; they fly over the ds_read+MFMA phase
        if (it + 1 < KCH / BK) {
            xsrc += BK; bsrc += BK;
            #pragma unroll
            for (int i = 0; i < 8; ++i) fa[i] = ((const float4*)xsrc)[i];
            #pragma unroll
            for (int i = 0; i < 4; ++i) fb[i] = ((const uint4*)bsrc)[i];
        }

        #pragma unroll
        for (int ks2 = 0; ks2 < 2; ++ks2) {
            bf16x8 af[4], bfr[4];
            #pragma unroll
            for (int i = 0; i < 4; ++i)
                af[i] = *((const bf16x8*)&As[(wm + i * 16 + l16) * LDSW + ks2 * 32 + quad * 8]);
            #pragma unroll
            for (int j = 0; j < 4; ++j)
                bfr[j] = *((const bf16x8*)&Bs[(wn + j * 16 + l16) * LDSW + ks2 * 32 + quad * 8]);
            #pragma unroll
            for (int i = 0; i < 4; ++i)
                #pragma unroll
                for (int j = 0; j < 4; ++j)
                    acc[i][j] = __builtin_amdgcn_mfma_f32_16x16x32_bf16(
                        af[i], bfr[j], acc[i][j], 0, 0, 0);
        }
    }

    float* hp = hidden_part + (long)ks * BATCH * D_MODEL;
    #pragma unroll
    for (int i = 0; i < 4; ++i)
        #pragma unroll
        for (int j = 0; j < 4; ++j) {
            const int col = n0 + wn + j * 16 + l16;
            #pragma unroll
            for (int r = 0; r < 4; ++r) {
                const int rowg = m0 + wm + i * 16 + quad * 4 + r;
                hp[(long)rowg * D_MODEL + col] = acc[i][j][r];
            }
        }
}

// ---------------------------------------------------------------------------
// Stage 2b: hidden_bf16 = bf16( sum of 16 f32 K-split partials )
// ---------------------------------------------------------------------------
__global__ __launch_bounds__(256) void reduce_kernel(
    const float* __restrict__ hp, unsigned short* __restrict__ hb)
{
    const int id = blockIdx.x * 256 + threadIdx.x;   // over 262144 float4
    const int S = BATCH * D_MODEL / 4;
    const float4* p = (const float4*)hp;
    float4 s = {0.f, 0.f, 0.f, 0.f};
    #pragma unroll
    for (int k = 0; k < KSPLIT; ++k) {
        float4 v = p[(long)k * S + id];
        s.x += v.x; s.y += v.y; s.z += v.z; s.w += v.w;
    }
    ushort4 o;
    o.x = f32_to_bf16(s.x); o.y = f32_to_bf16(s.y);
    o.z = f32_to_bf16(s.z); o.w = f32_to_bf16(s.w);
    ((ushort4*)hb)[id] = o;
}

// ---------------------------------------------------------------------------
// Stage 3: out = relu(hidden @ reps^T + bias)   M=4096 N=8192 K=256
// BK=64 (4 iters), reg-prefetch distance 1
// ---------------------------------------------------------------------------
__global__ __launch_bounds__(256, 3) void gemm2_kernel(
    const unsigned short* __restrict__ hb, const unsigned short* __restrict__ reps,
    const float* __restrict__ bias, float* __restrict__ out)
{
    __shared__ unsigned short As[128 * LDSW];
    __shared__ unsigned short Bs[128 * LDSW];

    const int m0 = blockIdx.y * 128;   // batch
    const int n0 = blockIdx.x * 128;   // features
    const int t = threadIdx.x;
    const int wave = t >> 6, lane = t & 63;
    const int wm = (wave >> 1) * 64, wn = (wave & 1) * 64;
    const int quad = lane >> 4, l16 = lane & 15;

    f32x4 acc[4][4];
    #pragma unroll
    for (int i = 0; i < 4; ++i)
        #pragma unroll
        for (int j = 0; j < 4; ++j)
            acc[i][j] = (f32x4){0.f, 0.f, 0.f, 0.f};

    const int row = t >> 1, half = t & 1;
    const unsigned short* asrc = hb + (long)(m0 + row) * D_MODEL + half * 32;
    const unsigned short* bsrc = reps + (long)(n0 + row) * D_MODEL + half * 32;
    unsigned short* aw = &As[row * LDSW + half * 32];
    unsigned short* bw = &Bs[row * LDSW + half * 32];

    uint4 pa[4], pb[4];
    #pragma unroll
    for (int i = 0; i < 4; ++i) pa[i] = ((const uint4*)asrc)[i];
    #pragma unroll
    for (int i = 0; i < 4; ++i) pb[i] = ((const uint4*)bsrc)[i];

    for (int it = 0; it < D_MODEL / BK; ++it) {
        __syncthreads();
        #pragma unroll
        for (int i = 0; i < 4; ++i)
            *(uint4*)(aw + i * 8) = pa[i];
        #pragma unroll
        for (int i = 0; i < 4; ++i)
            *(uint4*)(bw + i * 8) = pb[i];
        __syncthreads();

        if (it + 1 < D_MODEL / BK) {
            asrc += BK; bsrc += BK;
            #pragma unroll
            for (int i = 0; i < 4; ++i) pa[i] = ((const uint4*)asrc)[i];
            #pragma unroll
            for (int i = 0; i < 4; ++i) pb[i] = ((const uint4*)bsrc)[i];
        }

        #pragma unroll
        for (int ks2 = 0; ks2 < 2; ++ks2) {
            bf16x8 af[4], bfr[4];
            #pragma unroll
            for (int i = 0; i < 4; ++i)
                af[i] = *((const bf16x8*)&As[(wm + i * 16 + l16) * LDSW + ks2 * 32 + quad * 8]);
            #pragma unroll
            for (int j = 0; j < 4; ++j)
                bfr[j] = *((const bf16x8*)&Bs[(wn + j * 16 + l16) * LDSW + ks2 * 32 + quad * 8]);
            #pragma unroll
            for (int i = 0; i < 4; ++i)
                #pragma unroll
                for (int j = 0; j < 4; ++j)
                    acc[i][j] = __builtin_amdgcn_mfma_f32_16x16x32_bf16(
                        af[i], bfr[j], acc[i][j], 0, 0, 0);
        }
    }

    #pragma unroll
    for (int i = 0; i < 4; ++i)
        #pragma unroll
        for (int j = 0; j < 4; ++j) {
            const int col = n0 + wn + j * 16 + l16;
            const float bv = bias[col];
            #pragma unroll
            for (int r = 0; r < 4; ++r) {
                const int rowg = m0 + wm + i * 16 + quad * 4 + r;
                out[(long)rowg * N_FEAT + col] = fmaxf(acc[i][j][r] + bv, 0.f);
            }
        }
}

// ---------------------------------------------------------------------------
extern "C" void kernel_launch(void* const* d_in, const int* in_sizes, int n_in,
                              void* d_out, int out_size, void* d_ws, size_t ws_size,
                              hipStream_t stream) {
    const float* x    = (const float*)d_in[0];
    const float* proj = (const float*)d_in[1];
    const float* rw   = (const float*)d_in[2];
    const float* rb   = (const float*)d_in[3];
    const float* cb   = (const float*)d_in[4];
    const float* bias = (const float*)d_in[5];
    float* out = (float*)d_out;

    char* ws = (char*)d_ws;
    unsigned short* reps_bf = (unsigned short*)ws;                 // 4 MB
    unsigned short* repsT   = (unsigned short*)(ws + (4u << 20));  // 4 MB
    float* hid_prt          = (float*)(ws + (8u << 20));           // 64 MB (16 x 4 MB)
    unsigned short* hid_bf  = (unsigned short*)(ws + (72u << 20)); // 2 MB

    reps_kernel<<<N_FEAT / NT, 256, 0, stream>>>(proj, rw, rb, cb, reps_bf, repsT);
    gemm1_kernel<<<dim3(2, 32, KSPLIT), 256, 0, stream>>>(x, repsT, hid_prt);
    reduce_kernel<<<1024, 256, 0, stream>>>(hid_prt, hid_bf);
    gemm2_kernel<<<dim3(64, 32), 256, 0, stream>>>(hid_bf, reps_bf, bias, out);
}